// Round 6
// baseline (367.664 us; speedup 1.0000x reference)
//
#include <hip/hip_runtime.h>
#include <hip/hip_bf16.h>
#include <cstdint>
#include <cstddef>

#define BDIM 32768
#define IDIM 512
#define ODIM 512
#define KDIM 1024   // I+O
#define NDIM 2048   // 4*O

typedef __attribute__((ext_vector_type(8))) __bf16 bf16x8;
typedef __attribute__((ext_vector_type(4))) float f32x4;
typedef __attribute__((ext_vector_type(8))) unsigned short u16x8;

__device__ __forceinline__ unsigned short f2bf(float x) {
  union { float f; uint32_t u; } v; v.f = x;
  uint32_t r = v.u + 0x7FFFu + ((v.u >> 16) & 1u);  // RNE
  return (unsigned short)(r >> 16);
}

__device__ __forceinline__ float bf2f(unsigned short s) {
  union { uint32_t u; float f; } v; v.u = ((uint32_t)s) << 16;
  return v.f;
}

// ---------------- pack kernels: f32 -> bf16 ----------------

__global__ __launch_bounds__(256) void pack_a_kernel(const float* __restrict__ in,
                                                     const float* __restrict__ h,
                                                     unsigned short* __restrict__ A) {
  size_t t = (size_t)blockIdx.x * 256 + threadIdx.x;
  size_t e = t * 8;
  size_t b = e >> 10;
  int col = (int)(e & 1023);
  const float* src = (col < IDIM) ? (in + b * IDIM + col)
                                  : (h + b * ODIM + (col - IDIM));
  float4 v0 = ((const float4*)src)[0];
  float4 v1 = ((const float4*)src)[1];
  u16x8 r;
  r[0] = f2bf(v0.x); r[1] = f2bf(v0.y); r[2] = f2bf(v0.z); r[3] = f2bf(v0.w);
  r[4] = f2bf(v1.x); r[5] = f2bf(v1.y); r[6] = f2bf(v1.z); r[7] = f2bf(v1.w);
  *(u16x8*)(A + e) = r;
}

__global__ __launch_bounds__(256) void pack_w_kernel(const float* __restrict__ Wsrc,
                                                     unsigned short* __restrict__ Wb) {
  size_t t = (size_t)blockIdx.x * 256 + threadIdx.x;
  size_t e = t * 8;
  float4 v0 = ((const float4*)(Wsrc + e))[0];
  float4 v1 = ((const float4*)(Wsrc + e))[1];
  u16x8 r;
  r[0] = f2bf(v0.x); r[1] = f2bf(v0.y); r[2] = f2bf(v0.z); r[3] = f2bf(v0.w);
  r[4] = f2bf(v1.x); r[5] = f2bf(v1.y); r[6] = f2bf(v1.z); r[7] = f2bf(v1.w);
  *(u16x8*)(Wb + e) = r;
}

// ---------------- GEMM: 256x256 tile, BK=32, ring-4, frag-ordered LDS, reg-prefetch ----------------
// 8 waves (2M x 4N), per-wave 128x64 output = acc[8][4] f32x4.
// Ring of 4 x 32KB buffers. Fragment-ordered LDS (R4/R5): frag = 64 lanes x 16B
// contiguous -> ds_read_b128 at base+lane*16 => ZERO bank conflicts (verified).
// NEW (R6): one-tile register prefetch. Iter t: {VMW(4); BAR;
// ds_read tile t+1 frags -> F_next; stage tile t+3; MFMA burst from F_cur}.
// Reads and MFMAs are independent -> LDS latency hides under the burst.
// vmcnt FIFO: steady outstanding {t+1,t+2}=8; VMW(4) confirms tile t+1 (the
// one being read this iter). Taper: t=29 VMW(4) confirms 30; t=30 VMW(0).

#define BUFSZ 32768

#define BAR() do { asm volatile("" ::: "memory"); __builtin_amdgcn_s_barrier(); asm volatile("" ::: "memory"); } while (0)
#define VMW(n) asm volatile("s_waitcnt vmcnt(" #n ")" ::: "memory")

__device__ __forceinline__ void gll16(const unsigned short* src, char* ldsdst) {
  __builtin_amdgcn_global_load_lds(
      (const __attribute__((address_space(1))) void*)src,
      (__attribute__((address_space(3))) void*)ldsdst, 16, 0, 0);
}

// iter t: NBUF = (t+1)&3 (read source), stage dest = (NBUF+2)&3 = (t+3)&3
template<int NBUF, int VM, bool STG>
__device__ __forceinline__ void ktile(char* smem, const char* aR, const char* bR,
                                      const unsigned short* pA0, const unsigned short* pA1,
                                      const unsigned short* pB0, const unsigned short* pB1,
                                      int stOff,
                                      bf16x8 (&na)[8], bf16x8 (&nb)[4],
                                      const bf16x8 (&ca)[8], const bf16x8 (&cb)[4],
                                      f32x4 (&acc)[8][4]) {
  constexpr int NB = NBUF * BUFSZ;
  constexpr int DB = ((NBUF + 2) & 3) * BUFSZ;

  if (VM == 4)      VMW(4);
  else              VMW(0);
  BAR();

  // prefetch next tile's fragments into registers (independent of MFMA burst)
#pragma unroll
  for (int i = 0; i < 8; ++i) na[i] = *(const bf16x8*)(aR + NB + i * 1024);
#pragma unroll
  for (int j = 0; j < 4; ++j) nb[j] = *(const bf16x8*)(bR + NB + j * 1024);
  if (STG) {
    gll16(pA0, smem + DB + stOff);
    gll16(pA1, smem + DB + 8192 + stOff);
    gll16(pB0, smem + DB + 16384 + stOff);
    gll16(pB1, smem + DB + 24576 + stOff);
  }
  // MFMA burst from current (register-resident) fragments
  __builtin_amdgcn_s_setprio(1);
#pragma unroll
  for (int i = 0; i < 8; ++i)
#pragma unroll
    for (int j = 0; j < 4; ++j)
      acc[i][j] = __builtin_amdgcn_mfma_f32_16x16x32_bf16(ca[i], cb[j], acc[i][j], 0, 0, 0);
  __builtin_amdgcn_s_setprio(0);
  // pin emission order: reads first, then staging loads, then the MFMA cluster
  __builtin_amdgcn_sched_group_barrier(0x100, 12, 0);  // 12 DS_READ
  if (STG) __builtin_amdgcn_sched_group_barrier(0x20, 4, 0);  // 4 VMEM_READ (gll)
  __builtin_amdgcn_sched_group_barrier(0x8, 32, 0);    // 32 MFMA
}

__global__ __launch_bounds__(512, 2) void gemm_kernel(const unsigned short* __restrict__ A,
                                                      const unsigned short* __restrict__ Bt,
                                                      unsigned short* __restrict__ Cz) {
  extern __shared__ char smem[];
  const int tid = threadIdx.x;
  const int w = tid >> 6;
  const int lane = tid & 63;

  // XCD swizzle: each XCD gets a 16-mtile x 8-ntile chunk (B panel L2-resident)
  const int bid = blockIdx.x;                       // 0..1023
  const int swz = (bid & 7) * 128 + (bid >> 3);
  const int m0 = (swz >> 3) * 256;
  const int n0 = (swz & 7) * 256;

  const int wm = (w >> 2) * 128;   // 2 M-wave-rows
  const int wn = (w & 3) * 64;     // 4 N-wave-cols
  const int lrow = lane & 15;
  const int lk = (lane >> 4) * 8;

  // fragment read bases (linear within frag -> conflict-free)
  const char* aR = smem + (w >> 2) * 8192 + lane * 16;        // A frags (w>>2)*8 + 0..7
  const char* bR = smem + 16384 + (w & 3) * 4096 + lane * 16; // B frags (w&3)*4 + 0..3
  const int stOff = w * 1024 + lane * 16;

  // staging sources: wave w stages A-frags {w, w+8}, B-frags {w, w+8}
  const unsigned short* pA0 = A  + (size_t)(m0 + w * 16       + lrow) * KDIM + lk;
  const unsigned short* pA1 = A  + (size_t)(m0 + (8 + w) * 16 + lrow) * KDIM + lk;
  const unsigned short* pB0 = Bt + (size_t)(n0 + w * 16       + lrow) * KDIM + lk;
  const unsigned short* pB1 = Bt + (size_t)(n0 + (8 + w) * 16 + lrow) * KDIM + lk;

  f32x4 acc[8][4] = {};
  bf16x8 faA[8], faB[4], fbA[8], fbB[4];

  // prologue: stage tiles 0,1,2 into buffers 0,1,2 (FIFO order by tile)
#pragma unroll
  for (int t = 0; t < 3; ++t) {
    gll16(pA0 + t * 32, smem + t * BUFSZ + stOff);
    gll16(pA1 + t * 32, smem + t * BUFSZ + 8192 + stOff);
    gll16(pB0 + t * 32, smem + t * BUFSZ + 16384 + stOff);
    gll16(pB1 + t * 32, smem + t * BUFSZ + 24576 + stOff);
  }
  pA0 += 96; pA1 += 96; pB0 += 96; pB1 += 96;  // now point at tile 3's k-slice

  // preload: read tile 0 fragments into Fa (VMW(8) retires tile 0's 4 loads)
  VMW(8);
  BAR();
#pragma unroll
  for (int i = 0; i < 8; ++i) faA[i] = *(const bf16x8*)(aR + i * 1024);
#pragma unroll
  for (int j = 0; j < 4; ++j) faB[j] = *(const bf16x8*)(bR + j * 1024);

  // main loop: t = 0..27 (7 x 4), reg sets alternate Fa/Fb
  for (int tt = 0; tt < 7; ++tt) {
    ktile<1, 4, true>(smem, aR, bR, pA0, pA1, pB0, pB1, stOff, fbA, fbB, faA, faB, acc);
    pA0 += 32; pA1 += 32; pB0 += 32; pB1 += 32;
    ktile<2, 4, true>(smem, aR, bR, pA0, pA1, pB0, pB1, stOff, faA, faB, fbA, fbB, acc);
    pA0 += 32; pA1 += 32; pB0 += 32; pB1 += 32;
    ktile<3, 4, true>(smem, aR, bR, pA0, pA1, pB0, pB1, stOff, fbA, fbB, faA, faB, acc);
    pA0 += 32; pA1 += 32; pB0 += 32; pB1 += 32;
    ktile<0, 4, true>(smem, aR, bR, pA0, pA1, pB0, pB1, stOff, faA, faB, fbA, fbB, acc);
    pA0 += 32; pA1 += 32; pB0 += 32; pB1 += 32;
  }
  // t=28: read tile 29 (buf1), stage tile 31 (buf3), compute tile 28 (Fa)
  ktile<1, 4, true >(smem, aR, bR, pA0, pA1, pB0, pB1, stOff, fbA, fbB, faA, faB, acc);
  // t=29: read tile 30 (buf2), compute tile 29 (Fb)  [VMW(4) confirms tile 30]
  ktile<2, 4, false>(smem, aR, bR, pA0, pA1, pB0, pB1, stOff, faA, faB, fbA, fbB, acc);
  // t=30: read tile 31 (buf3), compute tile 30 (Fa)  [VMW(0) confirms tile 31]
  ktile<3, 0, false>(smem, aR, bR, pA0, pA1, pB0, pB1, stOff, fbA, fbB, faA, faB, acc);
  // t=31: compute tile 31 (Fb)
  __builtin_amdgcn_s_setprio(1);
#pragma unroll
  for (int i = 0; i < 8; ++i)
#pragma unroll
    for (int j = 0; j < 4; ++j)
      acc[i][j] = __builtin_amdgcn_mfma_f32_16x16x32_bf16(fbA[i], fbB[j], acc[i][j], 0, 0, 0);
  __builtin_amdgcn_s_setprio(0);

  // epilogue: C/D layout col = lane&15, row = (lane>>4)*4 + r
#pragma unroll
  for (int mi = 0; mi < 8; ++mi) {
#pragma unroll
    for (int ni = 0; ni < 4; ++ni) {
#pragma unroll
      for (int r = 0; r < 4; ++r) {
        const int row = m0 + wm + mi * 16 + (lane >> 4) * 4 + r;
        const int col = n0 + wn + ni * 16 + lrow;
        Cz[(size_t)row * NDIM + col] = f2bf(acc[mi][ni][r]);
      }
    }
  }
}

// ---------------- LayerNorm + gates ----------------

__global__ __launch_bounds__(256) void ln_gate_kernel(const unsigned short* __restrict__ z,
                                                      const float* __restrict__ c,
                                                      const float* __restrict__ gamma,
                                                      const float* __restrict__ beta,
                                                      float* __restrict__ out) {
  __shared__ float rowbuf[4][NDIM];  // 32 KB
  const int wave = threadIdx.x >> 6;
  const int lane = threadIdx.x & 63;
  const int row = blockIdx.x * 4 + wave;
  const unsigned short* zr = z + (size_t)row * NDIM;

  float s = 0.f, ss = 0.f;
#pragma unroll
  for (int j = 0; j < 4; ++j) {
    const int chunk = j * 64 + lane;
    u16x8 v = *(const u16x8*)(zr + chunk * 8);
    float f[8];
#pragma unroll
    for (int i2 = 0; i2 < 8; ++i2) {
      f[i2] = bf2f(v[i2]);
      s += f[i2];
      ss += f[i2] * f[i2];
    }
    float4* dst = (float4*)&rowbuf[wave][chunk * 8];
    dst[0] = make_float4(f[0], f[1], f[2], f[3]);
    dst[1] = make_float4(f[4], f[5], f[6], f[7]);
  }
#pragma unroll
  for (int off = 32; off > 0; off >>= 1) {
    s += __shfl_xor(s, off, 64);
    ss += __shfl_xor(ss, off, 64);
  }
  const float mean = s * (1.f / (float)NDIM);
  const float var = ss * (1.f / (float)NDIM) - mean * mean;
  const float inv = rsqrtf(var + 1e-5f);

  float* out_o = out + (size_t)row * ODIM;
  float* out_c = out + (size_t)BDIM * ODIM + (size_t)row * ODIM;
  const float* crow = c + (size_t)row * ODIM;

#pragma unroll
  for (int j = 0; j < 8; ++j) {
    const int o = j * 64 + lane;
    float zn[4];
#pragma unroll
    for (int g = 0; g < 4; ++g) {
      float v = (rowbuf[wave][g * ODIM + o] - mean) * inv;
      zn[g] = v * gamma[g * ODIM + o] + beta[g * ODIM + o];
    }
    const float fg = 1.f / (1.f + expf(-zn[0]));
    const float ig = 1.f / (1.f + expf(-zn[1]));
    const float og = 1.f / (1.f + expf(-zn[2]));
    const float x = zn[3];
    const float hs = 0.5f * x * (1.f + erff(x * 0.70710678118654752f));
    const float cc = fg * crow[o] + ig * hs;
    out_c[o] = cc;
    out_o[o] = og * cc;
  }
}

// ---------------- launch ----------------

extern "C" void kernel_launch(void* const* d_in, const int* in_sizes, int n_in,
                              void* d_out, int out_size, void* d_ws, size_t ws_size,
                              hipStream_t stream) {
  const float* input = (const float*)d_in[0];
  const float* h     = (const float*)d_in[1];
  const float* c     = (const float*)d_in[2];
  const float* W     = (const float*)d_in[3];
  const float* gamma = (const float*)d_in[4];
  const float* beta  = (const float*)d_in[5];

  unsigned short* A  = (unsigned short*)d_ws;                 // [32768,1024] bf16
  unsigned short* Wb = A + (size_t)BDIM * KDIM;               // [2048,1024] bf16
  unsigned short* z  = Wb + (size_t)NDIM * KDIM;              // [32768,2048] bf16
  float* out = (float*)d_out;

  hipFuncSetAttribute((const void*)gemm_kernel,
                      hipFuncAttributeMaxDynamicSharedMemorySize, 131072);

  pack_a_kernel<<<(BDIM * KDIM / 8) / 256, 256, 0, stream>>>(input, h, A);
  pack_w_kernel<<<(NDIM * KDIM / 8) / 256, 256, 0, stream>>>(W, Wb);
  gemm_kernel<<<dim3((BDIM / 256) * (NDIM / 256)), 512, 131072, stream>>>(A, Wb, z);
  ln_gate_kernel<<<BDIM / 4, 256, 0, stream>>>(z, c, gamma, beta, out);
}

// Round 7
// 287.781 us; speedup vs baseline: 1.2776x; 1.2776x over previous
//
#include <hip/hip_runtime.h>
#include <hip/hip_bf16.h>
#include <cstdint>
#include <cstddef>

#define BDIM 32768
#define IDIM 512
#define ODIM 512
#define KDIM 1024   // I+O
#define NDIM 2048   // 4*O

typedef __attribute__((ext_vector_type(8))) __bf16 bf16x8;
typedef __attribute__((ext_vector_type(4))) float f32x4;
typedef __attribute__((ext_vector_type(8))) unsigned short u16x8;

__device__ __forceinline__ unsigned short f2bf(float x) {
  union { float f; uint32_t u; } v; v.f = x;
  uint32_t r = v.u + 0x7FFFu + ((v.u >> 16) & 1u);  // RNE
  return (unsigned short)(r >> 16);
}

__device__ __forceinline__ float bf2f(unsigned short s) {
  union { uint32_t u; float f; } v; v.u = ((uint32_t)s) << 16;
  return v.f;
}

// ---------------- pack kernels: f32 -> bf16 ----------------

__global__ __launch_bounds__(256) void pack_a_kernel(const float* __restrict__ in,
                                                     const float* __restrict__ h,
                                                     unsigned short* __restrict__ A) {
  size_t t = (size_t)blockIdx.x * 256 + threadIdx.x;
  size_t e = t * 8;
  size_t b = e >> 10;
  int col = (int)(e & 1023);
  const float* src = (col < IDIM) ? (in + b * IDIM + col)
                                  : (h + b * ODIM + (col - IDIM));
  float4 v0 = ((const float4*)src)[0];
  float4 v1 = ((const float4*)src)[1];
  u16x8 r;
  r[0] = f2bf(v0.x); r[1] = f2bf(v0.y); r[2] = f2bf(v0.z); r[3] = f2bf(v0.w);
  r[4] = f2bf(v1.x); r[5] = f2bf(v1.y); r[6] = f2bf(v1.z); r[7] = f2bf(v1.w);
  *(u16x8*)(A + e) = r;
}

__global__ __launch_bounds__(256) void pack_w_kernel(const float* __restrict__ Wsrc,
                                                     unsigned short* __restrict__ Wb) {
  size_t t = (size_t)blockIdx.x * 256 + threadIdx.x;
  size_t e = t * 8;
  float4 v0 = ((const float4*)(Wsrc + e))[0];
  float4 v1 = ((const float4*)(Wsrc + e))[1];
  u16x8 r;
  r[0] = f2bf(v0.x); r[1] = f2bf(v0.y); r[2] = f2bf(v0.z); r[3] = f2bf(v0.w);
  r[4] = f2bf(v1.x); r[5] = f2bf(v1.y); r[6] = f2bf(v1.z); r[7] = f2bf(v1.w);
  *(u16x8*)(Wb + e) = r;
}

// ---------------- GEMM: 256x256 tile, BK=32, ring-4, frag-ordered LDS, phase-interleave ----------------
// 8 waves (2M x 4N), per-wave 128x64 output = acc[8][4] f32x4.
// Ring of 4 x 32KB buffers (128KB dynamic LDS). Fragment-ordered layout
// (verified ZERO conflicts in R4/R5): frag = 64 lanes x 16B contiguous,
// A = 16 frags x 1KB, B at +16384.
// R3's proven phase skeleton (152us): per tile, 2 phases of 16 MFMA; each
// phase's ds_reads + 2 staging gll are issued BEFORE a barrier, MFMA after
// -> read latency overlaps the previous MFMA burst still draining the pipe.
// Ring-4 => stage tile t+3 during tile t; vmcnt(8) at tile top retires
// exactly tile t's 4 loads (2-tile slack, no stall). Taper 8->8->4->0.
// Frag live-set <= 8 (64 VGPR): a0 dead before a1 read -> no spill (R6 lesson).

#define BUFSZ 32768

#define BAR() do { asm volatile("" ::: "memory"); __builtin_amdgcn_s_barrier(); asm volatile("" ::: "memory"); } while (0)
#define VMW(n) asm volatile("s_waitcnt vmcnt(" #n ")" ::: "memory")

__device__ __forceinline__ void gll16(const unsigned short* src, char* ldsdst) {
  __builtin_amdgcn_global_load_lds(
      (const __attribute__((address_space(1))) void*)src,
      (__attribute__((address_space(3))) void*)ldsdst, 16, 0, 0);
}

template<int BUF, int VM, bool STG>
__device__ __forceinline__ void ktile(char* smem, const char* aR, const char* bR,
                                      const unsigned short* pA0, const unsigned short* pA1,
                                      const unsigned short* pB0, const unsigned short* pB1,
                                      int stOff, f32x4 (&acc)[8][4]) {
  constexpr int CB = BUF * BUFSZ;
  constexpr int DB = ((BUF + 3) & 3) * BUFSZ;

  if (VM == 8)      VMW(8);
  else if (VM == 4) VMW(4);
  else              VMW(0);
  BAR();

  bf16x8 a0[4], qf[4], a1[4];
  // ---- phase 0: read A0-3 + B0-3; stage A-frags of tile t+3 ----
#pragma unroll
  for (int i = 0; i < 4; ++i) a0[i] = *(const bf16x8*)(aR + CB + i * 1024);
#pragma unroll
  for (int j = 0; j < 4; ++j) qf[j] = *(const bf16x8*)(bR + CB + j * 1024);
  if (STG) {
    gll16(pA0, smem + DB + stOff);
    gll16(pA1, smem + DB + 8192 + stOff);
  }
  BAR();
  __builtin_amdgcn_sched_barrier(0);
  __builtin_amdgcn_s_setprio(1);
#pragma unroll
  for (int i = 0; i < 4; ++i)
#pragma unroll
    for (int j = 0; j < 4; ++j)
      acc[i][j] = __builtin_amdgcn_mfma_f32_16x16x32_bf16(a0[i], qf[j], acc[i][j], 0, 0, 0);
  __builtin_amdgcn_s_setprio(0);
  __builtin_amdgcn_sched_barrier(0);
  BAR();

  // ---- phase 1: read A4-7; stage B-frags of tile t+3 ----
#pragma unroll
  for (int i = 0; i < 4; ++i) a1[i] = *(const bf16x8*)(aR + CB + (4 + i) * 1024);
  if (STG) {
    gll16(pB0, smem + DB + 16384 + stOff);
    gll16(pB1, smem + DB + 24576 + stOff);
  }
  BAR();
  __builtin_amdgcn_sched_barrier(0);
  __builtin_amdgcn_s_setprio(1);
#pragma unroll
  for (int i = 0; i < 4; ++i)
#pragma unroll
    for (int j = 0; j < 4; ++j)
      acc[4 + i][j] = __builtin_amdgcn_mfma_f32_16x16x32_bf16(a1[i], qf[j], acc[4 + i][j], 0, 0, 0);
  __builtin_amdgcn_s_setprio(0);
  __builtin_amdgcn_sched_barrier(0);
  // no trailing barrier: next tile's top barrier covers it
}

__global__ __launch_bounds__(512, 2) void gemm_kernel(const unsigned short* __restrict__ A,
                                                      const unsigned short* __restrict__ Bt,
                                                      unsigned short* __restrict__ Cz) {
  extern __shared__ char smem[];
  const int tid = threadIdx.x;
  const int w = tid >> 6;
  const int lane = tid & 63;

  // XCD swizzle: each XCD gets a 16-mtile x 8-ntile chunk (B panel L2-resident)
  const int bid = blockIdx.x;                       // 0..1023
  const int swz = (bid & 7) * 128 + (bid >> 3);
  const int m0 = (swz >> 3) * 256;
  const int n0 = (swz & 7) * 256;

  const int wm = (w >> 2) * 128;   // 2 M-wave-rows
  const int wn = (w & 3) * 64;     // 4 N-wave-cols
  const int lrow = lane & 15;
  const int lk = (lane >> 4) * 8;

  // fragment read bases (linear within frag -> conflict-free)
  const char* aR = smem + (w >> 2) * 8192 + lane * 16;        // A frags (w>>2)*8 + 0..7
  const char* bR = smem + 16384 + (w & 3) * 4096 + lane * 16; // B frags (w&3)*4 + 0..3
  const int stOff = w * 1024 + lane * 16;

  // staging sources: wave w stages A-frags {w, w+8}, B-frags {w, w+8}
  const unsigned short* pA0 = A  + (size_t)(m0 + w * 16       + lrow) * KDIM + lk;
  const unsigned short* pA1 = A  + (size_t)(m0 + (8 + w) * 16 + lrow) * KDIM + lk;
  const unsigned short* pB0 = Bt + (size_t)(n0 + w * 16       + lrow) * KDIM + lk;
  const unsigned short* pB1 = Bt + (size_t)(n0 + (8 + w) * 16 + lrow) * KDIM + lk;

  f32x4 acc[8][4] = {};

  // prologue: stage tiles 0,1,2 into buffers 0,1,2 (FIFO order by tile)
#pragma unroll
  for (int t = 0; t < 3; ++t) {
    gll16(pA0 + t * 32, smem + t * BUFSZ + stOff);
    gll16(pA1 + t * 32, smem + t * BUFSZ + 8192 + stOff);
    gll16(pB0 + t * 32, smem + t * BUFSZ + 16384 + stOff);
    gll16(pB1 + t * 32, smem + t * BUFSZ + 24576 + stOff);
  }
  pA0 += 96; pA1 += 96; pB0 += 96; pB1 += 96;  // now point at tile 3's k-slice

  // main loop: 32 K-tiles; tile t computes buf t&3, stages tile t+3 into buf (t+3)&3
  for (int tt = 0; tt < 7; ++tt) {
    ktile<0, 8, true>(smem, aR, bR, pA0, pA1, pB0, pB1, stOff, acc);
    pA0 += 32; pA1 += 32; pB0 += 32; pB1 += 32;
    ktile<1, 8, true>(smem, aR, bR, pA0, pA1, pB0, pB1, stOff, acc);
    pA0 += 32; pA1 += 32; pB0 += 32; pB1 += 32;
    ktile<2, 8, true>(smem, aR, bR, pA0, pA1, pB0, pB1, stOff, acc);
    pA0 += 32; pA1 += 32; pB0 += 32; pB1 += 32;
    ktile<3, 8, true>(smem, aR, bR, pA0, pA1, pB0, pB1, stOff, acc);
    pA0 += 32; pA1 += 32; pB0 += 32; pB1 += 32;
  }
  ktile<0, 8, true >(smem, aR, bR, pA0, pA1, pB0, pB1, stOff, acc);  // t28 stages t31
  ktile<1, 8, false>(smem, aR, bR, pA0, pA1, pB0, pB1, stOff, acc);  // t29
  ktile<2, 4, false>(smem, aR, bR, pA0, pA1, pB0, pB1, stOff, acc);  // t30
  ktile<3, 0, false>(smem, aR, bR, pA0, pA1, pB0, pB1, stOff, acc);  // t31

  // epilogue: C/D layout col = lane&15, row = (lane>>4)*4 + r
#pragma unroll
  for (int mi = 0; mi < 8; ++mi) {
#pragma unroll
    for (int ni = 0; ni < 4; ++ni) {
#pragma unroll
      for (int r = 0; r < 4; ++r) {
        const int row = m0 + wm + mi * 16 + (lane >> 4) * 4 + r;
        const int col = n0 + wn + ni * 16 + lrow;
        Cz[(size_t)row * NDIM + col] = f2bf(acc[mi][ni][r]);
      }
    }
  }
}

// ---------------- LayerNorm + gates ----------------

__global__ __launch_bounds__(256) void ln_gate_kernel(const unsigned short* __restrict__ z,
                                                      const float* __restrict__ c,
                                                      const float* __restrict__ gamma,
                                                      const float* __restrict__ beta,
                                                      float* __restrict__ out) {
  __shared__ float rowbuf[4][NDIM];  // 32 KB
  const int wave = threadIdx.x >> 6;
  const int lane = threadIdx.x & 63;
  const int row = blockIdx.x * 4 + wave;
  const unsigned short* zr = z + (size_t)row * NDIM;

  float s = 0.f, ss = 0.f;
#pragma unroll
  for (int j = 0; j < 4; ++j) {
    const int chunk = j * 64 + lane;
    u16x8 v = *(const u16x8*)(zr + chunk * 8);
    float f[8];
#pragma unroll
    for (int i2 = 0; i2 < 8; ++i2) {
      f[i2] = bf2f(v[i2]);
      s += f[i2];
      ss += f[i2] * f[i2];
    }
    float4* dst = (float4*)&rowbuf[wave][chunk * 8];
    dst[0] = make_float4(f[0], f[1], f[2], f[3]);
    dst[1] = make_float4(f[4], f[5], f[6], f[7]);
  }
#pragma unroll
  for (int off = 32; off > 0; off >>= 1) {
    s += __shfl_xor(s, off, 64);
    ss += __shfl_xor(ss, off, 64);
  }
  const float mean = s * (1.f / (float)NDIM);
  const float var = ss * (1.f / (float)NDIM) - mean * mean;
  const float inv = rsqrtf(var + 1e-5f);

  float* out_o = out + (size_t)row * ODIM;
  float* out_c = out + (size_t)BDIM * ODIM + (size_t)row * ODIM;
  const float* crow = c + (size_t)row * ODIM;

#pragma unroll
  for (int j = 0; j < 8; ++j) {
    const int o = j * 64 + lane;
    float zn[4];
#pragma unroll
    for (int g = 0; g < 4; ++g) {
      float v = (rowbuf[wave][g * ODIM + o] - mean) * inv;
      zn[g] = v * gamma[g * ODIM + o] + beta[g * ODIM + o];
    }
    const float fg = 1.f / (1.f + expf(-zn[0]));
    const float ig = 1.f / (1.f + expf(-zn[1]));
    const float og = 1.f / (1.f + expf(-zn[2]));
    const float x = zn[3];
    const float hs = 0.5f * x * (1.f + erff(x * 0.70710678118654752f));
    const float cc = fg * crow[o] + ig * hs;
    out_c[o] = cc;
    out_o[o] = og * cc;
  }
}

// ---------------- launch ----------------

extern "C" void kernel_launch(void* const* d_in, const int* in_sizes, int n_in,
                              void* d_out, int out_size, void* d_ws, size_t ws_size,
                              hipStream_t stream) {
  const float* input = (const float*)d_in[0];
  const float* h     = (const float*)d_in[1];
  const float* c     = (const float*)d_in[2];
  const float* W     = (const float*)d_in[3];
  const float* gamma = (const float*)d_in[4];
  const float* beta  = (const float*)d_in[5];

  unsigned short* A  = (unsigned short*)d_ws;                 // [32768,1024] bf16
  unsigned short* Wb = A + (size_t)BDIM * KDIM;               // [2048,1024] bf16
  unsigned short* z  = Wb + (size_t)NDIM * KDIM;              // [32768,2048] bf16
  float* out = (float*)d_out;

  hipFuncSetAttribute((const void*)gemm_kernel,
                      hipFuncAttributeMaxDynamicSharedMemorySize, 131072);

  pack_a_kernel<<<(BDIM * KDIM / 8) / 256, 256, 0, stream>>>(input, h, A);
  pack_w_kernel<<<(NDIM * KDIM / 8) / 256, 256, 0, stream>>>(W, Wb);
  gemm_kernel<<<dim3((BDIM / 256) * (NDIM / 256)), 512, 131072, stream>>>(A, Wb, z);
  ln_gate_kernel<<<BDIM / 4, 256, 0, stream>>>(z, c, gamma, beta, out);
}

// Round 8
// 285.303 us; speedup vs baseline: 1.2887x; 1.0087x over previous
//
#include <hip/hip_runtime.h>
#include <hip/hip_bf16.h>
#include <cstdint>
#include <cstddef>

#define BDIM 32768
#define IDIM 512
#define ODIM 512
#define KDIM 1024   // I+O
#define NDIM 2048   // 4*O

typedef __attribute__((ext_vector_type(8))) __bf16 bf16x8;
typedef __attribute__((ext_vector_type(4))) float f32x4;
typedef __attribute__((ext_vector_type(8))) unsigned short u16x8;

__device__ __forceinline__ unsigned short f2bf(float x) {
  union { float f; uint32_t u; } v; v.f = x;
  uint32_t r = v.u + 0x7FFFu + ((v.u >> 16) & 1u);  // RNE
  return (unsigned short)(r >> 16);
}

__device__ __forceinline__ float bf2f(unsigned short s) {
  union { uint32_t u; float f; } v; v.u = ((uint32_t)s) << 16;
  return v.f;
}

// ---------------- pack kernels: f32 -> bf16 ----------------

__global__ __launch_bounds__(256) void pack_a_kernel(const float* __restrict__ in,
                                                     const float* __restrict__ h,
                                                     unsigned short* __restrict__ A) {
  size_t t = (size_t)blockIdx.x * 256 + threadIdx.x;
  size_t e = t * 8;
  size_t b = e >> 10;
  int col = (int)(e & 1023);
  const float* src = (col < IDIM) ? (in + b * IDIM + col)
                                  : (h + b * ODIM + (col - IDIM));
  float4 v0 = ((const float4*)src)[0];
  float4 v1 = ((const float4*)src)[1];
  u16x8 r;
  r[0] = f2bf(v0.x); r[1] = f2bf(v0.y); r[2] = f2bf(v0.z); r[3] = f2bf(v0.w);
  r[4] = f2bf(v1.x); r[5] = f2bf(v1.y); r[6] = f2bf(v1.z); r[7] = f2bf(v1.w);
  *(u16x8*)(A + e) = r;
}

__global__ __launch_bounds__(256) void pack_w_kernel(const float* __restrict__ Wsrc,
                                                     unsigned short* __restrict__ Wb) {
  size_t t = (size_t)blockIdx.x * 256 + threadIdx.x;
  size_t e = t * 8;
  float4 v0 = ((const float4*)(Wsrc + e))[0];
  float4 v1 = ((const float4*)(Wsrc + e))[1];
  u16x8 r;
  r[0] = f2bf(v0.x); r[1] = f2bf(v0.y); r[2] = f2bf(v0.z); r[3] = f2bf(v0.w);
  r[4] = f2bf(v1.x); r[5] = f2bf(v1.y); r[6] = f2bf(v1.z); r[7] = f2bf(v1.w);
  *(u16x8*)(Wb + e) = r;
}

// ---------------- GEMM: 256x256 tile, BK=32, ring-4, frag-ordered LDS, phase-interleave ----------------
// 8 waves (2M x 4N), per-wave 128x64 output = acc[8][4] f32x4.
// Ring of 4 x 32KB buffers (128KB dynamic LDS). Fragment-ordered layout
// (verified ZERO conflicts in R4/R5): frag = 64 lanes x 16B contiguous,
// A = 16 frags x 1KB, B at +16384.
// R3's proven phase skeleton (152us): per tile, 2 phases of 16 MFMA; each
// phase's ds_reads + 2 staging gll are issued BEFORE a barrier, MFMA after
// -> read latency overlaps the previous MFMA burst still draining the pipe.
// Ring-4 => stage tile t+3 during tile t; vmcnt(8) at tile top retires
// exactly tile t's 4 loads (2-tile slack, no stall). Taper 8->8->4->0.
// Frag live-set <= 8 (64 VGPR): a0 dead before a1 read -> no spill (R6 lesson).

#define BUFSZ 32768

#define BAR() do { asm volatile("" ::: "memory"); __builtin_amdgcn_s_barrier(); asm volatile("" ::: "memory"); } while (0)
#define VMW(n) asm volatile("s_waitcnt vmcnt(" #n ")" ::: "memory")

__device__ __forceinline__ void gll16(const unsigned short* src, char* ldsdst) {
  __builtin_amdgcn_global_load_lds(
      (const __attribute__((address_space(1))) void*)src,
      (__attribute__((address_space(3))) void*)ldsdst, 16, 0, 0);
}

template<int BUF, int VM, bool STG>
__device__ __forceinline__ void ktile(char* smem, const char* aR, const char* bR,
                                      const unsigned short* pA0, const unsigned short* pA1,
                                      const unsigned short* pB0, const unsigned short* pB1,
                                      int stOff, f32x4 (&acc)[8][4]) {
  constexpr int CB = BUF * BUFSZ;
  constexpr int DB = ((BUF + 3) & 3) * BUFSZ;

  if (VM == 8)      VMW(8);
  else if (VM == 4) VMW(4);
  else              VMW(0);
  BAR();

  bf16x8 a0[4], qf[4], a1[4];
  // ---- phase 0: read A0-3 + B0-3; stage A-frags of tile t+3 ----
#pragma unroll
  for (int i = 0; i < 4; ++i) a0[i] = *(const bf16x8*)(aR + CB + i * 1024);
#pragma unroll
  for (int j = 0; j < 4; ++j) qf[j] = *(const bf16x8*)(bR + CB + j * 1024);
  if (STG) {
    gll16(pA0, smem + DB + stOff);
    gll16(pA1, smem + DB + 8192 + stOff);
  }
  BAR();
  __builtin_amdgcn_sched_barrier(0);
  __builtin_amdgcn_s_setprio(1);
#pragma unroll
  for (int i = 0; i < 4; ++i)
#pragma unroll
    for (int j = 0; j < 4; ++j)
      acc[i][j] = __builtin_amdgcn_mfma_f32_16x16x32_bf16(a0[i], qf[j], acc[i][j], 0, 0, 0);
  __builtin_amdgcn_s_setprio(0);
  __builtin_amdgcn_sched_barrier(0);
  BAR();

  // ---- phase 1: read A4-7; stage B-frags of tile t+3 ----
#pragma unroll
  for (int i = 0; i < 4; ++i) a1[i] = *(const bf16x8*)(aR + CB + (4 + i) * 1024);
  if (STG) {
    gll16(pB0, smem + DB + 16384 + stOff);
    gll16(pB1, smem + DB + 24576 + stOff);
  }
  BAR();
  __builtin_amdgcn_sched_barrier(0);
  __builtin_amdgcn_s_setprio(1);
#pragma unroll
  for (int i = 0; i < 4; ++i)
#pragma unroll
    for (int j = 0; j < 4; ++j)
      acc[4 + i][j] = __builtin_amdgcn_mfma_f32_16x16x32_bf16(a1[i], qf[j], acc[4 + i][j], 0, 0, 0);
  __builtin_amdgcn_s_setprio(0);
  __builtin_amdgcn_sched_barrier(0);
  // no trailing barrier: next tile's top barrier covers it
}

__global__ __launch_bounds__(512, 2) void gemm_kernel(const unsigned short* __restrict__ A,
                                                      const unsigned short* __restrict__ Bt,
                                                      unsigned short* __restrict__ Cz) {
  extern __shared__ char smem[];
  const int tid = threadIdx.x;
  const int w = tid >> 6;
  const int lane = tid & 63;

  // XCD swizzle: each XCD gets a 16-mtile x 8-ntile chunk (B panel L2-resident)
  const int bid = blockIdx.x;                       // 0..1023
  const int swz = (bid & 7) * 128 + (bid >> 3);
  const int m0 = (swz >> 3) * 256;
  const int n0 = (swz & 7) * 256;

  const int wm = (w >> 2) * 128;   // 2 M-wave-rows
  const int wn = (w & 3) * 64;     // 4 N-wave-cols
  const int lrow = lane & 15;
  const int lk = (lane >> 4) * 8;

  // fragment read bases (linear within frag -> conflict-free)
  const char* aR = smem + (w >> 2) * 8192 + lane * 16;        // A frags (w>>2)*8 + 0..7
  const char* bR = smem + 16384 + (w & 3) * 4096 + lane * 16; // B frags (w&3)*4 + 0..3
  const int stOff = w * 1024 + lane * 16;

  // staging sources: wave w stages A-frags {w, w+8}, B-frags {w, w+8}
  const unsigned short* pA0 = A  + (size_t)(m0 + w * 16       + lrow) * KDIM + lk;
  const unsigned short* pA1 = A  + (size_t)(m0 + (8 + w) * 16 + lrow) * KDIM + lk;
  const unsigned short* pB0 = Bt + (size_t)(n0 + w * 16       + lrow) * KDIM + lk;
  const unsigned short* pB1 = Bt + (size_t)(n0 + (8 + w) * 16 + lrow) * KDIM + lk;

  f32x4 acc[8][4] = {};

  // prologue: stage tiles 0,1,2 into buffers 0,1,2 (FIFO order by tile)
#pragma unroll
  for (int t = 0; t < 3; ++t) {
    gll16(pA0 + t * 32, smem + t * BUFSZ + stOff);
    gll16(pA1 + t * 32, smem + t * BUFSZ + 8192 + stOff);
    gll16(pB0 + t * 32, smem + t * BUFSZ + 16384 + stOff);
    gll16(pB1 + t * 32, smem + t * BUFSZ + 24576 + stOff);
  }
  pA0 += 96; pA1 += 96; pB0 += 96; pB1 += 96;  // now point at tile 3's k-slice

  // main loop: 32 K-tiles; tile t computes buf t&3, stages tile t+3 into buf (t+3)&3
  for (int tt = 0; tt < 7; ++tt) {
    ktile<0, 8, true>(smem, aR, bR, pA0, pA1, pB0, pB1, stOff, acc);
    pA0 += 32; pA1 += 32; pB0 += 32; pB1 += 32;
    ktile<1, 8, true>(smem, aR, bR, pA0, pA1, pB0, pB1, stOff, acc);
    pA0 += 32; pA1 += 32; pB0 += 32; pB1 += 32;
    ktile<2, 8, true>(smem, aR, bR, pA0, pA1, pB0, pB1, stOff, acc);
    pA0 += 32; pA1 += 32; pB0 += 32; pB1 += 32;
    ktile<3, 8, true>(smem, aR, bR, pA0, pA1, pB0, pB1, stOff, acc);
    pA0 += 32; pA1 += 32; pB0 += 32; pB1 += 32;
  }
  ktile<0, 8, true >(smem, aR, bR, pA0, pA1, pB0, pB1, stOff, acc);  // t28 stages t31
  ktile<1, 8, false>(smem, aR, bR, pA0, pA1, pB0, pB1, stOff, acc);  // t29
  ktile<2, 4, false>(smem, aR, bR, pA0, pA1, pB0, pB1, stOff, acc);  // t30
  ktile<3, 0, false>(smem, aR, bR, pA0, pA1, pB0, pB1, stOff, acc);  // t31

  // epilogue: C/D layout col = lane&15, row = (lane>>4)*4 + r
#pragma unroll
  for (int mi = 0; mi < 8; ++mi) {
#pragma unroll
    for (int ni = 0; ni < 4; ++ni) {
#pragma unroll
      for (int r = 0; r < 4; ++r) {
        const int row = m0 + wm + mi * 16 + (lane >> 4) * 4 + r;
        const int col = n0 + wn + ni * 16 + lrow;
        Cz[(size_t)row * NDIM + col] = f2bf(acc[mi][ni][r]);
      }
    }
  }
}

// ---------------- LayerNorm + gates ----------------

__global__ __launch_bounds__(256) void ln_gate_kernel(const unsigned short* __restrict__ z,
                                                      const float* __restrict__ c,
                                                      const float* __restrict__ gamma,
                                                      const float* __restrict__ beta,
                                                      float* __restrict__ out) {
  __shared__ float rowbuf[4][NDIM];  // 32 KB
  const int wave = threadIdx.x >> 6;
  const int lane = threadIdx.x & 63;
  const int row = blockIdx.x * 4 + wave;
  const unsigned short* zr = z + (size_t)row * NDIM;

  float s = 0.f, ss = 0.f;
#pragma unroll
  for (int j = 0; j < 4; ++j) {
    const int chunk = j * 64 + lane;
    u16x8 v = *(const u16x8*)(zr + chunk * 8);
    float f[8];
#pragma unroll
    for (int i2 = 0; i2 < 8; ++i2) {
      f[i2] = bf2f(v[i2]);
      s += f[i2];
      ss += f[i2] * f[i2];
    }
    float4* dst = (float4*)&rowbuf[wave][chunk * 8];
    dst[0] = make_float4(f[0], f[1], f[2], f[3]);
    dst[1] = make_float4(f[4], f[5], f[6], f[7]);
  }
#pragma unroll
  for (int off = 32; off > 0; off >>= 1) {
    s += __shfl_xor(s, off, 64);
    ss += __shfl_xor(ss, off, 64);
  }
  const float mean = s * (1.f / (float)NDIM);
  const float var = ss * (1.f / (float)NDIM) - mean * mean;
  const float inv = rsqrtf(var + 1e-5f);

  float* out_o = out + (size_t)row * ODIM;
  float* out_c = out + (size_t)BDIM * ODIM + (size_t)row * ODIM;
  const float* crow = c + (size_t)row * ODIM;

#pragma unroll
  for (int j = 0; j < 8; ++j) {
    const int o = j * 64 + lane;
    float zn[4];
#pragma unroll
    for (int g = 0; g < 4; ++g) {
      float v = (rowbuf[wave][g * ODIM + o] - mean) * inv;
      zn[g] = v * gamma[g * ODIM + o] + beta[g * ODIM + o];
    }
    const float fg = 1.f / (1.f + expf(-zn[0]));
    const float ig = 1.f / (1.f + expf(-zn[1]));
    const float og = 1.f / (1.f + expf(-zn[2]));
    const float x = zn[3];
    const float hs = 0.5f * x * (1.f + erff(x * 0.70710678118654752f));
    const float cc = fg * crow[o] + ig * hs;
    out_c[o] = cc;
    out_o[o] = og * cc;
  }
}

// ---------------- launch ----------------

extern "C" void kernel_launch(void* const* d_in, const int* in_sizes, int n_in,
                              void* d_out, int out_size, void* d_ws, size_t ws_size,
                              hipStream_t stream) {
  const float* input = (const float*)d_in[0];
  const float* h     = (const float*)d_in[1];
  const float* c     = (const float*)d_in[2];
  const float* W     = (const float*)d_in[3];
  const float* gamma = (const float*)d_in[4];
  const float* beta  = (const float*)d_in[5];

  unsigned short* A  = (unsigned short*)d_ws;                 // [32768,1024] bf16
  unsigned short* Wb = A + (size_t)BDIM * KDIM;               // [2048,1024] bf16
  unsigned short* z  = Wb + (size_t)NDIM * KDIM;              // [32768,2048] bf16
  float* out = (float*)d_out;

  hipFuncSetAttribute((const void*)gemm_kernel,
                      hipFuncAttributeMaxDynamicSharedMemorySize, 131072);

  pack_a_kernel<<<(BDIM * KDIM / 8) / 256, 256, 0, stream>>>(input, h, A);
  pack_w_kernel<<<(NDIM * KDIM / 8) / 256, 256, 0, stream>>>(W, Wb);
  gemm_kernel<<<dim3((BDIM / 256) * (NDIM / 256)), 512, 131072, stream>>>(A, Wb, z);
  ln_gate_kernel<<<BDIM / 4, 256, 0, stream>>>(z, c, gamma, beta, out);
}

// Round 9
// 282.193 us; speedup vs baseline: 1.3029x; 1.0110x over previous
//
#include <hip/hip_runtime.h>
#include <hip/hip_bf16.h>
#include <cstdint>
#include <cstddef>

#define BDIM 32768
#define IDIM 512
#define ODIM 512
#define KDIM 1024   // I+O
#define NDIM 2048   // 4*O

typedef __attribute__((ext_vector_type(8))) __bf16 bf16x8;
typedef __attribute__((ext_vector_type(4))) float f32x4;
typedef __attribute__((ext_vector_type(8))) unsigned short u16x8;

__device__ __forceinline__ unsigned short f2bf(float x) {
  union { float f; uint32_t u; } v; v.f = x;
  uint32_t r = v.u + 0x7FFFu + ((v.u >> 16) & 1u);  // RNE
  return (unsigned short)(r >> 16);
}

__device__ __forceinline__ float bf2f(unsigned short s) {
  union { uint32_t u; float f; } v; v.u = ((uint32_t)s) << 16;
  return v.f;
}

// ---------------- pack kernels: f32 -> bf16 ----------------

__global__ __launch_bounds__(256) void pack_a_kernel(const float* __restrict__ in,
                                                     const float* __restrict__ h,
                                                     unsigned short* __restrict__ A) {
  size_t t = (size_t)blockIdx.x * 256 + threadIdx.x;
  size_t e = t * 8;
  size_t b = e >> 10;
  int col = (int)(e & 1023);
  const float* src = (col < IDIM) ? (in + b * IDIM + col)
                                  : (h + b * ODIM + (col - IDIM));
  float4 v0 = ((const float4*)src)[0];
  float4 v1 = ((const float4*)src)[1];
  u16x8 r;
  r[0] = f2bf(v0.x); r[1] = f2bf(v0.y); r[2] = f2bf(v0.z); r[3] = f2bf(v0.w);
  r[4] = f2bf(v1.x); r[5] = f2bf(v1.y); r[6] = f2bf(v1.z); r[7] = f2bf(v1.w);
  *(u16x8*)(A + e) = r;
}

__global__ __launch_bounds__(256) void pack_w_kernel(const float* __restrict__ Wsrc,
                                                     unsigned short* __restrict__ Wb) {
  size_t t = (size_t)blockIdx.x * 256 + threadIdx.x;
  size_t e = t * 8;
  float4 v0 = ((const float4*)(Wsrc + e))[0];
  float4 v1 = ((const float4*)(Wsrc + e))[1];
  u16x8 r;
  r[0] = f2bf(v0.x); r[1] = f2bf(v0.y); r[2] = f2bf(v0.z); r[3] = f2bf(v0.w);
  r[4] = f2bf(v1.x); r[5] = f2bf(v1.y); r[6] = f2bf(v1.z); r[7] = f2bf(v1.w);
  *(u16x8*)(Wb + e) = r;
}

// ---------------- GEMM: 256x256 tile, BK=64, dbuf-2, 4-phase (m201 schedule) ----------------
// 8 waves (2M x 4N), per-wave 128x64 output = acc[8][4] f32x4.
// LDS: 2 buffers x 64KB. Per buffer: A = 32 frags x 1KB (frag idx = ks*16+mf,
// ks = k-slice 0/1 of BK=64, mf = 16-row m-frag), B at +32768 same with nf.
// Fragment = 64 lanes x 16B contiguous -> ds_read_b128 linear => 0 conflicts
// (verified R4-R8). Staging quarters (16KB = one ks-half of A or B): wave w
// writes frags {w, w+8}; per-lane pre-permuted global source.
// Per K-tile: 4 phases, each {ds_read 8|4 x b128; 2 x global_load_lds; BAR;
// lgkmcnt(0); setprio(1); 16 MFMA; setprio(0); [VMW(4) before BAR at P2/P4]}.
// vmcnt FIFO (pairs): stage order Aks0,Bks0,Aks1,Bks1 of tile t+1 at phases
// P1..P4 of tile t; VMW(4) at P2-end confirms {Aks1,Bks1}(t) for P3, at
// P4-end confirms {Aks0,Bks0}(t+1) for next P1. Retired pairs were issued
// 3-4 phases (~1000cy) earlier -> no stall. Reads issue BEFORE each barrier
// so barrier-wait absorbs LDS latency; lgkmcnt(0) after is near-free.

#define BAR() do { asm volatile("" ::: "memory"); __builtin_amdgcn_s_barrier(); asm volatile("" ::: "memory"); } while (0)
#define VMW(n) asm volatile("s_waitcnt vmcnt(" #n ")" ::: "memory")
#define LGKM0() do { asm volatile("s_waitcnt lgkmcnt(0)" ::: "memory"); __builtin_amdgcn_sched_barrier(0); } while (0)

__device__ __forceinline__ void gll16(const unsigned short* src, char* ldsdst) {
  __builtin_amdgcn_global_load_lds(
      (const __attribute__((address_space(1))) void*)src,
      (__attribute__((address_space(3))) void*)ldsdst, 16, 0, 0);
}

template<int CBUF, bool STG, bool FINAL>
__device__ __forceinline__ void ktile64(char* smem, const char* aRd, const char* bRd,
                                        const unsigned short* paLo, const unsigned short* paHi,
                                        const unsigned short* pbLo, const unsigned short* pbHi,
                                        int wland, f32x4 (&acc)[8][4]) {
  constexpr int CB = CBUF * 65536;        // compute buffer
  constexpr int SB = (CBUF ^ 1) * 65536;  // stage buffer (tile t+1)
  bf16x8 a[4], b0[4], b1[4];

  // ---- P1: A[mf0-3,ks0] + B[ks0]; stage A-ks0(t+1) ----
#pragma unroll
  for (int i = 0; i < 4; ++i) a[i] = *(const bf16x8*)(aRd + CB + i * 1024);
#pragma unroll
  for (int j = 0; j < 4; ++j) b0[j] = *(const bf16x8*)(bRd + CB + j * 1024);
  if (STG) { gll16(paLo, smem + SB + wland); gll16(paHi, smem + SB + 8192 + wland); }
  BAR(); LGKM0();
  __builtin_amdgcn_s_setprio(1);
#pragma unroll
  for (int i = 0; i < 4; ++i)
#pragma unroll
    for (int j = 0; j < 4; ++j)
      acc[i][j] = __builtin_amdgcn_mfma_f32_16x16x32_bf16(a[i], b0[j], acc[i][j], 0, 0, 0);
  __builtin_amdgcn_s_setprio(0);
  __builtin_amdgcn_sched_barrier(0);
  BAR();

  // ---- P2: A[mf4-7,ks0]; stage B-ks0(t+1); confirm {Aks1,Bks1}(t) ----
#pragma unroll
  for (int i = 0; i < 4; ++i) a[i] = *(const bf16x8*)(aRd + CB + (4 + i) * 1024);
  if (STG) { gll16(pbLo, smem + SB + 32768 + wland); gll16(pbHi, smem + SB + 40960 + wland); }
  BAR(); LGKM0();
  __builtin_amdgcn_s_setprio(1);
#pragma unroll
  for (int i = 0; i < 4; ++i)
#pragma unroll
    for (int j = 0; j < 4; ++j)
      acc[4 + i][j] = __builtin_amdgcn_mfma_f32_16x16x32_bf16(a[i], b0[j], acc[4 + i][j], 0, 0, 0);
  __builtin_amdgcn_s_setprio(0);
  __builtin_amdgcn_sched_barrier(0);
  if (FINAL) VMW(0); else VMW(4);
  BAR();

  // ---- P3: A[mf0-3,ks1] + B[ks1]; stage A-ks1(t+1) ----
#pragma unroll
  for (int i = 0; i < 4; ++i) a[i] = *(const bf16x8*)(aRd + CB + 16384 + i * 1024);
#pragma unroll
  for (int j = 0; j < 4; ++j) b1[j] = *(const bf16x8*)(bRd + CB + 16384 + j * 1024);
  if (STG) { gll16(paLo + 32, smem + SB + 16384 + wland); gll16(paHi + 32, smem + SB + 24576 + wland); }
  BAR(); LGKM0();
  __builtin_amdgcn_s_setprio(1);
#pragma unroll
  for (int i = 0; i < 4; ++i)
#pragma unroll
    for (int j = 0; j < 4; ++j)
      acc[i][j] = __builtin_amdgcn_mfma_f32_16x16x32_bf16(a[i], b1[j], acc[i][j], 0, 0, 0);
  __builtin_amdgcn_s_setprio(0);
  __builtin_amdgcn_sched_barrier(0);
  BAR();

  // ---- P4: A[mf4-7,ks1]; stage B-ks1(t+1); confirm {Aks0,Bks0}(t+1) ----
#pragma unroll
  for (int i = 0; i < 4; ++i) a[i] = *(const bf16x8*)(aRd + CB + 16384 + (4 + i) * 1024);
  if (STG) { gll16(pbLo + 32, smem + SB + 49152 + wland); gll16(pbHi + 32, smem + SB + 57344 + wland); }
  BAR(); LGKM0();
  __builtin_amdgcn_s_setprio(1);
#pragma unroll
  for (int i = 0; i < 4; ++i)
#pragma unroll
    for (int j = 0; j < 4; ++j)
      acc[4 + i][j] = __builtin_amdgcn_mfma_f32_16x16x32_bf16(a[i], b1[j], acc[4 + i][j], 0, 0, 0);
  __builtin_amdgcn_s_setprio(0);
  __builtin_amdgcn_sched_barrier(0);
  if (!FINAL) VMW(4);
  BAR();
}

__global__ __launch_bounds__(512, 2) void gemm_kernel(const unsigned short* __restrict__ A,
                                                      const unsigned short* __restrict__ Bt,
                                                      unsigned short* __restrict__ Cz) {
  extern __shared__ char smem[];
  const int tid = threadIdx.x;
  const int w = tid >> 6;
  const int lane = tid & 63;

  // XCD swizzle: each XCD gets a 16-mtile x 8-ntile chunk (B panel L2-resident)
  const int bid = blockIdx.x;                       // 0..1023
  const int swz = (bid & 7) * 128 + (bid >> 3);
  const int m0 = (swz >> 3) * 256;
  const int n0 = (swz & 7) * 256;

  const int wm = (w >> 2) * 128;   // 2 M-wave-rows
  const int wn = (w & 3) * 64;     // 4 N-wave-cols
  const int lrow = lane & 15;
  const int lk = (lane >> 4) * 8;

  // fragment read bases (linear within frag -> conflict-free)
  const char* aRd = smem + (w >> 2) * 8192 + lane * 16;          // A frags (w>>2)*8 + i
  const char* bRd = smem + 32768 + (w & 3) * 4096 + lane * 16;   // B frags (w&3)*4 + j
  const int wland = w * 1024 + lane * 16;

  // staging sources: wave w stages frags {w, w+8} of each quarter
  const unsigned short* paLo = A  + (size_t)(m0 + w * 16       + lrow) * KDIM + lk;
  const unsigned short* paHi = A  + (size_t)(m0 + (8 + w) * 16 + lrow) * KDIM + lk;
  const unsigned short* pbLo = Bt + (size_t)(n0 + w * 16       + lrow) * KDIM + lk;
  const unsigned short* pbHi = Bt + (size_t)(n0 + (8 + w) * 16 + lrow) * KDIM + lk;

  f32x4 acc[8][4] = {};

  // prologue: stage tile 0 into buf0, quarter order Aks0, Bks0, Aks1, Bks1
  gll16(paLo,      smem + wland);
  gll16(paHi,      smem + 8192 + wland);
  gll16(pbLo,      smem + 32768 + wland);
  gll16(pbHi,      smem + 40960 + wland);
  gll16(paLo + 32, smem + 16384 + wland);
  gll16(paHi + 32, smem + 24576 + wland);
  gll16(pbLo + 32, smem + 49152 + wland);
  gll16(pbHi + 32, smem + 57344 + wland);
  VMW(4);   // confirm Aks0(0), Bks0(0)
  BAR();
  paLo += 64; paHi += 64; pbLo += 64; pbHi += 64;  // stage pointers -> tile 1

  // main loop: 16 K-tiles (BK=64); tile t computes buf t&1, stages t+1 into buf (t+1)&1
  for (int tt = 0; tt < 7; ++tt) {
    ktile64<0, true, false>(smem, aRd, bRd, paLo, paHi, pbLo, pbHi, wland, acc);
    paLo += 64; paHi += 64; pbLo += 64; pbHi += 64;
    ktile64<1, true, false>(smem, aRd, bRd, paLo, paHi, pbLo, pbHi, wland, acc);
    paLo += 64; paHi += 64; pbLo += 64; pbHi += 64;
  }
  ktile64<0, true,  false>(smem, aRd, bRd, paLo, paHi, pbLo, pbHi, wland, acc);  // t14 stages t15
  ktile64<1, false, true >(smem, aRd, bRd, paLo, paHi, pbLo, pbHi, wland, acc);  // t15

  // epilogue: C/D layout col = lane&15, row = (lane>>4)*4 + r
#pragma unroll
  for (int mi = 0; mi < 8; ++mi) {
#pragma unroll
    for (int ni = 0; ni < 4; ++ni) {
#pragma unroll
      for (int r = 0; r < 4; ++r) {
        const int row = m0 + wm + mi * 16 + (lane >> 4) * 4 + r;
        const int col = n0 + wn + ni * 16 + lrow;
        Cz[(size_t)row * NDIM + col] = f2bf(acc[mi][ni][r]);
      }
    }
  }
}

// ---------------- LayerNorm + gates ----------------

__global__ __launch_bounds__(256) void ln_gate_kernel(const unsigned short* __restrict__ z,
                                                      const float* __restrict__ c,
                                                      const float* __restrict__ gamma,
                                                      const float* __restrict__ beta,
                                                      float* __restrict__ out) {
  __shared__ float rowbuf[4][NDIM];  // 32 KB
  const int wave = threadIdx.x >> 6;
  const int lane = threadIdx.x & 63;
  const int row = blockIdx.x * 4 + wave;
  const unsigned short* zr = z + (size_t)row * NDIM;

  float s = 0.f, ss = 0.f;
#pragma unroll
  for (int j = 0; j < 4; ++j) {
    const int chunk = j * 64 + lane;
    u16x8 v = *(const u16x8*)(zr + chunk * 8);
    float f[8];
#pragma unroll
    for (int i2 = 0; i2 < 8; ++i2) {
      f[i2] = bf2f(v[i2]);
      s += f[i2];
      ss += f[i2] * f[i2];
    }
    float4* dst = (float4*)&rowbuf[wave][chunk * 8];
    dst[0] = make_float4(f[0], f[1], f[2], f[3]);
    dst[1] = make_float4(f[4], f[5], f[6], f[7]);
  }
#pragma unroll
  for (int off = 32; off > 0; off >>= 1) {
    s += __shfl_xor(s, off, 64);
    ss += __shfl_xor(ss, off, 64);
  }
  const float mean = s * (1.f / (float)NDIM);
  const float var = ss * (1.f / (float)NDIM) - mean * mean;
  const float inv = rsqrtf(var + 1e-5f);

  float* out_o = out + (size_t)row * ODIM;
  float* out_c = out + (size_t)BDIM * ODIM + (size_t)row * ODIM;
  const float* crow = c + (size_t)row * ODIM;

#pragma unroll
  for (int j = 0; j < 8; ++j) {
    const int o = j * 64 + lane;
    float zn[4];
#pragma unroll
    for (int g = 0; g < 4; ++g) {
      float v = (rowbuf[wave][g * ODIM + o] - mean) * inv;
      zn[g] = v * gamma[g * ODIM + o] + beta[g * ODIM + o];
    }
    const float fg = 1.f / (1.f + expf(-zn[0]));
    const float ig = 1.f / (1.f + expf(-zn[1]));
    const float og = 1.f / (1.f + expf(-zn[2]));
    const float x = zn[3];
    const float hs = 0.5f * x * (1.f + erff(x * 0.70710678118654752f));
    const float cc = fg * crow[o] + ig * hs;
    out_c[o] = cc;
    out_o[o] = og * cc;
  }
}

// ---------------- launch ----------------

extern "C" void kernel_launch(void* const* d_in, const int* in_sizes, int n_in,
                              void* d_out, int out_size, void* d_ws, size_t ws_size,
                              hipStream_t stream) {
  const float* input = (const float*)d_in[0];
  const float* h     = (const float*)d_in[1];
  const float* c     = (const float*)d_in[2];
  const float* W     = (const float*)d_in[3];
  const float* gamma = (const float*)d_in[4];
  const float* beta  = (const float*)d_in[5];

  unsigned short* A  = (unsigned short*)d_ws;                 // [32768,1024] bf16
  unsigned short* Wb = A + (size_t)BDIM * KDIM;               // [2048,1024] bf16
  unsigned short* z  = Wb + (size_t)NDIM * KDIM;              // [32768,2048] bf16
  float* out = (float*)d_out;

  hipFuncSetAttribute((const void*)gemm_kernel,
                      hipFuncAttributeMaxDynamicSharedMemorySize, 131072);

  pack_a_kernel<<<(BDIM * KDIM / 8) / 256, 256, 0, stream>>>(input, h, A);
  pack_w_kernel<<<(NDIM * KDIM / 8) / 256, 256, 0, stream>>>(W, Wb);
  gemm_kernel<<<dim3((BDIM / 256) * (NDIM / 256)), 512, 131072, stream>>>(A, Wb, z);
  ln_gate_kernel<<<BDIM / 4, 256, 0, stream>>>(z, c, gamma, beta, out);
}